// Round 8
// baseline (778.102 us; speedup 1.0000x reference)
//
#include <hip/hip_runtime.h>
#include <hip/hip_bf16.h>
#include <stdint.h>
#include <stddef.h>

typedef __hip_bfloat16 bf16;
typedef __attribute__((ext_vector_type(8))) short short8;
typedef __attribute__((ext_vector_type(4))) float f32x4;

#define EPI_NONE 0
#define EPI_SILU 1
#define EPI_RES  2
#define OUT_BF16   0
#define OUT_F32    1
#define OUT_SPLIT  2
#define OUT_VT     3   // write C transposed into VT[b][d][token], token = row
#define OUT_ESTATS 4   // write E=exp(S-m_blk) bf16 + per-col block max/sumexp

__device__ __forceinline__ void gll16(const bf16* g, char* l) {
    __builtin_amdgcn_global_load_lds(
        (const __attribute__((address_space(1))) void*)g,
        (__attribute__((address_space(3))) void*)l, 16, 0, 0);
}

struct Segs { const bf16* A[3]; const bf16* B[3]; };

// ---------------------------------------------------------------------------
// K-segmented m97-structure bf16 GEMM.
//   C = sum_s A_seg[s] @ B_seg[s]^T over NSEG segments, each kseg K-columns.
// bf16x3 split products expressed as segments (A:{Qh,Qh,Ql}, B:{Kh,Kl,Kh}).
// AEC=1: A-operand is E (bf16) scaled on the fly by cScale[blk(row)][k]
// (reg-staged global->reg->mul->ds_write to the same linear LDS slot the
// gll16 path uses; source column stays pre-swizzled => read path unchanged).
// LDS XOR-swizzle => 0 bank conflicts (verified r3). XCD-aware bijective
// block swizzle (grids %8==0; verified r5). OUT_ESTATS: E-write + fused
// block-column max/sumexp partials (m_blk broadcast via LDS).
// ---------------------------------------------------------------------------
template<int NSEG, int BN, int EPI, int OUT, int AEC>
__global__ __launch_bounds__(256)
void gemm_seg(Segs sg, void* __restrict__ Cp, bf16* __restrict__ Clo,
              const float* __restrict__ Res,
              float* __restrict__ mp, float* __restrict__ zp,
              const float* __restrict__ cScale,
              int kseg, int lda, int ldb, int ldc, int ldr,
              unsigned long long sA, unsigned long long sB, unsigned long long sC)
{
    constexpr int NWF = BN / 32;          // col fragments per wave

    const size_t zA = (size_t)blockIdx.z * sA;
    const size_t zB = (size_t)blockIdx.z * sB;
    const size_t zC = (size_t)blockIdx.z * sC;

    // XCD-aware bijective swizzle on the (x,y) plane (nwg % 8 == 0)
    unsigned nwg = gridDim.x * gridDim.y;
    unsigned lin = blockIdx.y * gridDim.x + blockIdx.x;
    unsigned cpx = nwg >> 3;
    unsigned swz = (lin & 7) * cpx + (lin >> 3);
    unsigned bxs = swz % gridDim.x, bys = swz / gridDim.x;

    const int t    = threadIdx.x;
    const int w    = t >> 6;
    const int lane = t & 63;
    const int wr   = w >> 1, wc = w & 1;
    const int lo   = lane & 15, hi = lane >> 4;
    const int brow = bys * 128;
    const int bcol = bxs * BN;

    __shared__ bf16 As[128 * 64];
    __shared__ bf16 Bs[BN * 64];
    __shared__ float smst[(OUT == OUT_ESTATS) ? 512 : 4];

    f32x4 acc[4][NWF];
#pragma unroll
    for (int m = 0; m < 4; ++m)
#pragma unroll
        for (int n = 0; n < NWF; ++n)
            acc[m][n] = (f32x4){0.f, 0.f, 0.f, 0.f};

    const int r0 = t >> 3;                             // row in 32-row stripe
    const int cswz = ((t & 7) ^ ((t >> 3) & 7)) * 8;   // inverse-swizzled src
    const int rA7  = lo & 7;                           // read-side row parity

    const float* cb = nullptr;
    if constexpr (AEC)
        cb = cScale + ((size_t)blockIdx.z * 32 + (brow >> 7)) * 4096;

#pragma unroll
    for (int s = 0; s < NSEG; ++s) {
        const bf16* Ag = sg.A[s] + zA;
        const bf16* Bg = sg.B[s] + zB;
        for (int k0 = 0; k0 < kseg; k0 += 64) {
            if constexpr (AEC) {
                // reg-staged A: E * c  -> same linear LDS slot as gll16 path
#pragma unroll
                for (int i = 0; i < 4; ++i) {
                    int r = i * 32 + r0;
                    const bf16* ag = Ag + (size_t)(brow + r) * lda + (k0 + cswz);
                    short8 ev = *(const short8*)ag;
                    float4 c0 = *(const float4*)(cb + k0 + cswz);
                    float4 c1 = *(const float4*)(cb + k0 + cswz + 4);
                    float cf[8] = {c0.x, c0.y, c0.z, c0.w, c1.x, c1.y, c1.z, c1.w};
                    short8 pv;
#pragma unroll
                    for (int j = 0; j < 8; ++j) {
                        unsigned short us = (unsigned short)ev[j];
                        bf16 eb = *(bf16*)&us;
                        bf16 pb = __float2bfloat16(__bfloat162float(eb) * cf[j]);
                        pv[j] = *(short*)&pb;
                    }
                    *(short8*)((char*)As + i * 4096 + (size_t)t * 16) = pv;
                }
            } else {
#pragma unroll
                for (int i = 0; i < 4; ++i) {
                    int r = i * 32 + r0;
                    gll16(Ag + (size_t)(brow + r) * lda + (k0 + cswz),
                          (char*)As + i * 4096 + w * 1024);
                }
            }
#pragma unroll
            for (int i = 0; i < NWF; ++i) {
                int r = i * 32 + r0;
                gll16(Bg + (size_t)(bcol + r) * ldb + (k0 + cswz),
                      (char*)Bs + i * 4096 + w * 1024);
            }
            __syncthreads();

#pragma unroll
            for (int kk = 0; kk < 64; kk += 32) {
                short8 aH[4], bH[NWF];
#pragma unroll
                for (int m = 0; m < 4; ++m) {
                    int idx = (wr * 64 + m * 16 + lo) * 64 +
                              ((((kk >> 3) + hi) ^ rA7) * 8);
                    aH[m] = *(const short8*)&As[idx];
                }
#pragma unroll
                for (int n = 0; n < NWF; ++n) {
                    int idx = (wc * (BN / 2) + n * 16 + lo) * 64 +
                              ((((kk >> 3) + hi) ^ rA7) * 8);
                    bH[n] = *(const short8*)&Bs[idx];
                }
#pragma unroll
                for (int m = 0; m < 4; ++m)
#pragma unroll
                    for (int n = 0; n < NWF; ++n)
                        acc[m][n] = __builtin_amdgcn_mfma_f32_16x16x32_bf16(
                            aH[m], bH[n], acc[m][n], 0, 0, 0);
            }
            __syncthreads();
        }
    }

    if constexpr (OUT == OUT_ESTATS) {
        // ---- phase A: full 128-row block-column max ----
        float mb[NWF];
#pragma unroll
        for (int n = 0; n < NWF; ++n) {
            float ml = acc[0][n][0];
#pragma unroll
            for (int m = 0; m < 4; ++m)
#pragma unroll
                for (int j = 0; j < 4; ++j) ml = fmaxf(ml, acc[m][n][j]);
            ml = fmaxf(ml, __shfl_xor(ml, 16));
            ml = fmaxf(ml, __shfl_xor(ml, 32));
            if (hi == 0) smst[wr * 128 + wc * (BN / 2) + n * 16 + lo] = ml;
        }
        __syncthreads();
#pragma unroll
        for (int n = 0; n < NWF; ++n) {
            int c = wc * (BN / 2) + n * 16 + lo;
            mb[n] = fmaxf(smst[c], smst[128 + c]);
        }
        // ---- phase B: E write + z partial ----
        float zsum[NWF];
#pragma unroll
        for (int n = 0; n < NWF; ++n) {
            zsum[n] = 0.f;
            int col = bcol + wc * (BN / 2) + n * 16 + lo;
#pragma unroll
            for (int m = 0; m < 4; ++m)
#pragma unroll
                for (int j = 0; j < 4; ++j) {
                    int row = brow + wr * 64 + m * 16 + hi * 4 + j;
                    float e = __expf(acc[m][n][j] - mb[n]);
                    zsum[n] += e;
                    ((bf16*)Cp)[(size_t)row * ldc + col] = __float2bfloat16(e);
                }
        }
        // ---- phase C: z reduce -> mp/zp ----
        __syncthreads();
#pragma unroll
        for (int n = 0; n < NWF; ++n) {
            float zl = zsum[n];
            zl += __shfl_xor(zl, 16);
            zl += __shfl_xor(zl, 32);
            if (hi == 0) smst[256 + wr * 128 + wc * (BN / 2) + n * 16 + lo] = zl;
        }
        __syncthreads();
        if (t < 128) {
            float m0 = smst[t],       m1 = smst[128 + t];
            float z0 = smst[256 + t], z1 = smst[384 + t];
            size_t o = (size_t)(brow >> 7) * 4096 + bcol + t;
            mp[o] = fmaxf(m0, m1);
            zp[o] = z0 + z1;
        }
        return;
    }

    // ---- generic epilogues ----
#pragma unroll
    for (int m = 0; m < 4; ++m) {
#pragma unroll
        for (int n = 0; n < NWF; ++n) {
            if constexpr (OUT == OUT_VT) {
                int row0 = brow + wr * 64 + m * 16 + hi * 4;
                int col  = bcol + wc * (BN / 2) + n * 16 + lo;    // d index
                int bb = row0 >> 12, n0 = row0 & 4095;
                unsigned short u[4];
#pragma unroll
                for (int j = 0; j < 4; ++j) {
                    bf16 vb = __float2bfloat16(acc[m][n][j]);
                    u[j] = *(unsigned short*)&vb;
                }
                ushort4 pack = {u[0], u[1], u[2], u[3]};
                *(ushort4*)&((bf16*)Cp)[((size_t)(bb * 512 + col) << 12) + n0] = pack;
            } else {
#pragma unroll
                for (int j = 0; j < 4; ++j) {
                    int row = brow + wr * 64 + m * 16 + hi * 4 + j;
                    int col = bcol + wc * (BN / 2) + n * 16 + lo;
                    size_t idx = (size_t)row * ldc + col + zC;
                    float v = acc[m][n][j];
                    if (EPI == EPI_SILU) v = v / (1.f + __expf(-v));
                    if (EPI == EPI_RES)  v += Res[(size_t)row * ldr + col];
                    if (OUT == OUT_F32) {
                        ((float*)Cp)[idx] = v;
                    } else if (OUT == OUT_BF16) {
                        ((bf16*)Cp)[idx] = __float2bfloat16(v);
                    } else if (OUT == OUT_SPLIT) {
                        bf16 vh = __float2bfloat16(v);
                        ((bf16*)Cp)[idx] = vh;
                        Clo[idx] = __float2bfloat16(v - __bfloat162float(vh));
                    }
                }
            }
        }
    }
}

// ---- split x fp32 -> (hi, lo) bf16 pair, vectorized ----
__global__ void split_x_kernel(const float* __restrict__ x,
                               bf16* __restrict__ xh, bf16* __restrict__ xl)
{
    size_t i = ((size_t)blockIdx.x * 256 + threadIdx.x) * 4;
    float4 v = *(const float4*)(x + i);
    float vv[4] = {v.x, v.y, v.z, v.w};
    unsigned short rh[4], rl[4];
#pragma unroll
    for (int j = 0; j < 4; ++j) {
        bf16 h_ = __float2bfloat16(vv[j]);
        bf16 l_ = __float2bfloat16(vv[j] - __bfloat162float(h_));
        rh[j] = *(unsigned short*)&h_;
        rl[j] = *(unsigned short*)&l_;
    }
    ushort4 oh = {rh[0], rh[1], rh[2], rh[3]};
    ushort4 ol = {rl[0], rl[1], rl[2], rl[3]};
    *(ushort4*)(xh + i) = oh;
    *(ushort4*)(xl + i) = ol;
}

// ---- transpose + split all 10 weights in one dispatch (z = weight idx) ----
struct WPack { const float* W[10]; bf16* H[10]; bf16* L[10]; };

__global__ void transw_all_kernel(WPack p)
{
    const float* W  = p.W[blockIdx.z];
    bf16* WTh = p.H[blockIdx.z];
    bf16* WTl = p.L[blockIdx.z];
    __shared__ float tile[32][33];
    int bx = blockIdx.x * 32, by = blockIdx.y * 32;
    int tx = threadIdx.x, ty = threadIdx.y;      // (32, 8)
#pragma unroll
    for (int i = 0; i < 32; i += 8)
        tile[ty + i][tx] = W[(size_t)(by + ty + i) * 512 + bx + tx];
    __syncthreads();
#pragma unroll
    for (int i = 0; i < 32; i += 8) {
        float v = tile[tx][ty + i];
        bf16 h_ = __float2bfloat16(v);
        size_t idx = (size_t)(bx + ty + i) * 512 + by + tx;
        WTh[idx] = h_;
        if (WTl) WTl[idx] = __float2bfloat16(v - __bfloat162float(h_));
    }
}

// ---- combine 32 row-block partials -> per-(block,col) PV scale c ----
__global__ void colstats_comb_kernel(const float* __restrict__ mp,
                                     const float* __restrict__ zp,
                                     float* __restrict__ cB)
{
    int col = blockIdx.x * 256 + threadIdx.x;
    float m = -1e30f;
#pragma unroll
    for (int i = 0; i < 32; ++i) m = fmaxf(m, mp[i * 4096 + col]);
    float z = 0.f;
#pragma unroll
    for (int i = 0; i < 32; ++i) z += zp[i * 4096 + col] * __expf(mp[i * 4096 + col] - m);
    float r = 1.f / z;
#pragma unroll
    for (int i = 0; i < 32; ++i)
        cB[i * 4096 + col] = __expf(mp[i * 4096 + col] - m) * r;
}

// ---------------------------------------------------------------------------
extern "C" void kernel_launch(void* const* d_in, const int* in_sizes, int n_in,
                              void* d_out, int out_size, void* d_ws, size_t ws_size,
                              hipStream_t stream)
{
    const int B = 4, N = 4096, D = 512;
    const size_t MALL = (size_t)B * N;          // 16384
    const size_t ND = MALL * D;                 // 8.4M elems
    const size_t NN = (size_t)N * N;            // 16.7M elems
    const size_t WW = (size_t)D * D;            // 262144
    const float* x = (const float*)d_in[0];
    const float* Wf[10];
    for (int i = 0; i < 10; ++i) Wf[i] = (const float*)d_in[1 + i];
    // Wf: 0 qW1, 1 qW2, 2 kW1, 3 kW2, 4 vW1, 5 vW2, 6 aWq, 7 aWk, 8 aWv, 9 Wout

    char* ws = (char*)d_ws;
    size_t off = 0;
    auto carve = [&](size_t bytes) -> char* {
        char* p = ws + off;
        off = (off + bytes + 255) & ~(size_t)255;
        return p;
    };

    // 7 consecutive 32-MiB planes. Lifetimes:
    //   P0: x split (xh,xl)           -> E[0]
    //   P1: (t1v,hv) then t1h(q|k)    -> E[1]
    //   P2: t1l(q|k)                  -> E[2]
    //   P3: hh(q|k)                   -> E[3]
    //   P4: hl(q|k)                   -> O (lo half) + mp/zp/cB (hi half)
    //   F : QKh [16384][1024]
    //   G : QKl [16384][1024]
    // E planes P0..P3 are consecutive => uniform stride NN for z-batched PV.
    const size_t PLANE = NN * 2;                 // 33,554,432 B
    bf16* P0 = (bf16*)carve(PLANE);
    bf16* P1 = (bf16*)carve(PLANE);
    bf16* P2 = (bf16*)carve(PLANE);
    bf16* P3 = (bf16*)carve(PLANE);
    bf16* P4 = (bf16*)carve(PLANE);
    bf16* F  = (bf16*)carve(PLANE);
    bf16* G  = (bf16*)carve(PLANE);
    bf16* VT = (bf16*)carve((size_t)B * D * N * 2);           // 16 MiB
    bf16* wc1H = (bf16*)carve(2 * WW * 2);  bf16* wc1L = (bf16*)carve(2 * WW * 2);
    bf16* wc2H = (bf16*)carve(2 * WW * 2);  bf16* wc2L = (bf16*)carve(2 * WW * 2);
    bf16* wcAH = (bf16*)carve(2 * WW * 2);  bf16* wcAL = (bf16*)carve(2 * WW * 2);
    bf16* wv1H = (bf16*)carve(WW * 2);
    bf16* wv2H = (bf16*)carve(WW * 2);
    bf16* wv3H = (bf16*)carve(WW * 2);
    bf16* woH  = (bf16*)carve(WW * 2);      bf16* woL  = (bf16*)carve(WW * 2);
    // total carve = 260,571,136 B <= 262,701,056 proven writable (round 2).

    bf16* xh  = P0;  bf16* xl  = P0 + ND;
    bf16* t1v = P1;  bf16* hv  = P1 + ND;        // v-branch scratch (first)
    bf16* t1h = P1;  bf16* t1l = P2;             // qk chain [16384][1024]
    bf16* hh  = P3;  bf16* hl  = P4;
    bf16* QKh = F;   bf16* QKl = G;              // cols 0-511 = Q, 512-1023 = K
    bf16* E_all = P0;                            // E planes, stride NN
    bf16* O   = P4;                              // 16 MiB, lo half of P4
    float* mp = (float*)((char*)P4 + PLANE / 2); // stats in P4 hi half
    float* zp = mp + 32 * 4096;
    float* cB = zp + 32 * 4096;                  // [B][32][4096]
    (void)in_sizes; (void)n_in; (void)out_size; (void)ws_size;

    // ---- input split + all weight transposes ----
    split_x_kernel<<<dim3((unsigned)(ND / 1024)), 256, 0, stream>>>(x, xh, xl);
    WPack wp;
    wp.W[0] = Wf[0]; wp.H[0] = wc1H;      wp.L[0] = wc1L;        // qW1
    wp.W[1] = Wf[2]; wp.H[1] = wc1H + WW; wp.L[1] = wc1L + WW;   // kW1
    wp.W[2] = Wf[1]; wp.H[2] = wc2H;      wp.L[2] = wc2L;        // qW2
    wp.W[3] = Wf[3]; wp.H[3] = wc2H + WW; wp.L[3] = wc2L + WW;   // kW2
    wp.W[4] = Wf[6]; wp.H[4] = wcAH;      wp.L[4] = wcAL;        // aWq
    wp.W[5] = Wf[7]; wp.H[5] = wcAH + WW; wp.L[5] = wcAL + WW;   // aWk
    wp.W[6] = Wf[4]; wp.H[6] = wv1H;      wp.L[6] = nullptr;     // vW1
    wp.W[7] = Wf[5]; wp.H[7] = wv2H;      wp.L[7] = nullptr;     // vW2
    wp.W[8] = Wf[8]; wp.H[8] = wv3H;      wp.L[8] = nullptr;     // aWv
    wp.W[9] = Wf[9]; wp.H[9] = woH;       wp.L[9] = woL;         // Wout
    transw_all_kernel<<<dim3(16, 16, 10), dim3(32, 8), 0, stream>>>(wp);

    auto seg1 = [](const bf16* a, const bf16* b) {
        Segs s; s.A[0] = a; s.A[1] = a; s.A[2] = a;
        s.B[0] = b; s.B[1] = b; s.B[2] = b; return s;
    };
    auto seg2 = [](const bf16* a0, const bf16* a1,
                   const bf16* b0, const bf16* b1) {
        Segs s; s.A[0] = a0; s.A[1] = a1; s.A[2] = a1;
        s.B[0] = b0; s.B[1] = b1; s.B[2] = b1; return s;
    };
    auto seg3 = [](const bf16* ah, const bf16* al,
                   const bf16* bh, const bf16* bl) {
        Segs s; s.A[0] = ah; s.A[1] = ah; s.A[2] = al;
        s.B[0] = bh; s.B[1] = bl; s.B[2] = bh; return s;
    };

    // ---- v branch (plain bf16, BN=64; scratch in P1; VT direct) ----
    gemm_seg<1, 64, EPI_SILU, OUT_BF16, 0><<<dim3(8, 128), 256, 0, stream>>>(
        seg1(xh, wv1H), t1v, nullptr, nullptr, nullptr, nullptr, nullptr,
        512, 512, 512, 512, 512, 0, 0, 0);
    gemm_seg<1, 64, EPI_RES, OUT_BF16, 0><<<dim3(8, 128), 256, 0, stream>>>(
        seg1(t1v, wv2H), hv, nullptr, x, nullptr, nullptr, nullptr,
        512, 512, 512, 512, 512, 0, 0, 0);
    gemm_seg<1, 64, EPI_NONE, OUT_VT, 0><<<dim3(8, 128), 256, 0, stream>>>(
        seg1(hv, wv3H), VT, nullptr, nullptr, nullptr, nullptr, nullptr,
        512, 512, 512, 512, 512, 0, 0, 0);

    // ---- q+k branches (bf16x3 as 3 K-segments, BN=128) ----
    gemm_seg<3, 128, EPI_SILU, OUT_SPLIT, 0><<<dim3(8, 128), 256, 0, stream>>>(
        seg3(xh, xl, wc1H, wc1L), t1h, t1l, nullptr, nullptr, nullptr, nullptr,
        512, 512, 512, 1024, 512, 0, 0, 0);
    gemm_seg<3, 128, EPI_RES, OUT_SPLIT, 0><<<dim3(4, 128, 2), 256, 0, stream>>>(
        seg3(t1h, t1l, wc2H, wc2L), hh, hl, x, nullptr, nullptr, nullptr,
        512, 1024, 512, 1024, 512, 512, WW, 512);
    gemm_seg<3, 128, EPI_NONE, OUT_SPLIT, 0><<<dim3(4, 128, 2), 256, 0, stream>>>(
        seg3(hh, hl, wcAH, wcAL), QKh, QKl, nullptr, nullptr, nullptr, nullptr,
        512, 1024, 512, 1024, 512, 512, WW, 512);

    // ---- per batch: QK^T writes E + block stats; comb -> c ----
    for (int b = 0; b < B; ++b) {
        size_t boff = (size_t)b * N * 1024;
        gemm_seg<3, 128, EPI_NONE, OUT_ESTATS, 0><<<dim3(32, 32), 256, 0, stream>>>(
            seg3(QKh + boff, QKl + boff, QKh + boff + 512, QKl + boff + 512),
            E_all + (size_t)b * NN, nullptr, nullptr, mp, zp, nullptr,
            512, 1024, 1024, 4096, 4096, 0, 0, 0);
        colstats_comb_kernel<<<16, 256, 0, stream>>>(mp, zp, cB + (size_t)b * 32 * 4096);
    }

    // ---- z-batched PV: O[b] = (E[b] * c[b]) @ VT[b]^T  (AEC staging) ----
    gemm_seg<1, 64, EPI_NONE, OUT_BF16, 1><<<dim3(8, 32, 4), 256, 0, stream>>>(
        seg1(E_all, VT), O, nullptr, nullptr, nullptr, nullptr, cB,
        4096, 4096, 4096, 512, 512,
        NN, (unsigned long long)D * N, (unsigned long long)N * D);

    // ---- final projection: d_out = O @ Wout (2 segments, BN=64) ----
    gemm_seg<2, 64, EPI_NONE, OUT_F32, 0><<<dim3(8, 128), 256, 0, stream>>>(
        seg2(O, O, woH, woL), d_out, nullptr, nullptr, nullptr, nullptr, nullptr,
        512, 512, 512, 512, 512, 0, 0, 0);
}

// Round 9
// 425.797 us; speedup vs baseline: 1.8274x; 1.8274x over previous
//
#include <hip/hip_runtime.h>
#include <hip/hip_bf16.h>
#include <stdint.h>
#include <stddef.h>

typedef _Float16 f16;
typedef __attribute__((ext_vector_type(8))) _Float16 f16x8;
typedef __attribute__((ext_vector_type(4))) float f32x4;

#define EPI_NONE 0
#define EPI_SILU 1
#define EPI_RES  2
#define OUT_F16    0
#define OUT_F32    1
#define OUT_VT     3   // write C transposed into VT[b][d][token], token = row
#define OUT_ESTATS 4   // write E=exp(S-m_blk) f16 + per-col block max/sumexp

__device__ __forceinline__ void gll16(const f16* g, char* l) {
    __builtin_amdgcn_global_load_lds(
        (const __attribute__((address_space(1))) void*)g,
        (__attribute__((address_space(3))) void*)l, 16, 0, 0);
}

// ---------------------------------------------------------------------------
// fp16 m97-structure GEMM: C = A @ B^T, f32 accumulate (exact per-dot).
// 128xBN tile, BK=64, 4 waves (2x2), mfma_f32_16x16x32_f16.
// LDS XOR-swizzle => 0 bank conflicts (verified r3). XCD-aware bijective
// block swizzle (grids %8==0; verified r5: ideal FETCH).
// AEC=1 (PV): B-operand (VT tile) scaled on the fly by cScale[qblk][k],
// reg-staged with one-step prefetch (latency drains into the barrier);
// A-operand stays on the async gll16 path.
// OUT_ESTATS: E=exp(S-m_blk) f16 write + block-column max/sumexp partials.
// ---------------------------------------------------------------------------
template<int BN, int EPI, int OUT, int AEC>
__global__ __launch_bounds__(256)
void gemm_f16(const f16* __restrict__ A, const f16* __restrict__ Bm,
              void* __restrict__ Cp, const float* __restrict__ Res,
              float* __restrict__ mp, float* __restrict__ zp,
              const float* __restrict__ cScale,
              int kseg, int lda, int ldb, int ldc, int ldr,
              unsigned long long sA, unsigned long long sB, unsigned long long sC)
{
    constexpr int NWF = BN / 32;

    const f16* Ag = A + (size_t)blockIdx.z * sA;
    const f16* Bg = Bm + (size_t)blockIdx.z * sB;
    const size_t zC = (size_t)blockIdx.z * sC;

    // XCD-aware bijective swizzle on the (x,y) plane (nwg % 8 == 0)
    unsigned nwg = gridDim.x * gridDim.y;
    unsigned lin = blockIdx.y * gridDim.x + blockIdx.x;
    unsigned cpx = nwg >> 3;
    unsigned swz = (lin & 7) * cpx + (lin >> 3);
    unsigned bxs = swz % gridDim.x, bys = swz / gridDim.x;

    const int t    = threadIdx.x;
    const int w    = t >> 6;
    const int lane = t & 63;
    const int wr   = w >> 1, wc = w & 1;
    const int lo   = lane & 15, hi = lane >> 4;
    const int brow = bys * 128;
    const int bcol = bxs * BN;

    __shared__ f16 As[128 * 64];
    __shared__ f16 Bs[BN * 64];
    __shared__ float smst[(OUT == OUT_ESTATS) ? 512 : 4];

    f32x4 acc[4][NWF];
#pragma unroll
    for (int m = 0; m < 4; ++m)
#pragma unroll
        for (int n = 0; n < NWF; ++n)
            acc[m][n] = (f32x4){0.f, 0.f, 0.f, 0.f};

    const int r0 = t >> 3;                             // row in 32-row stripe
    const int cswz = ((t & 7) ^ ((t >> 3) & 7)) * 8;   // inverse-swizzled src
    const int rA7  = lo & 7;                           // read-side row parity

    const float* cb = nullptr;
    f16x8 bq[NWF];
    float4 cq0, cq1;
    if constexpr (AEC) {
        cb = cScale + ((size_t)blockIdx.z * 32 + (brow >> 7)) * 4096;
#pragma unroll
        for (int i = 0; i < NWF; ++i)
            bq[i] = *(const f16x8*)(Bg + (size_t)(bcol + i * 32 + r0) * ldb + cswz);
        cq0 = *(const float4*)(cb + cswz);
        cq1 = *(const float4*)(cb + cswz + 4);
    }

    for (int k0 = 0; k0 < kseg; k0 += 64) {
#pragma unroll
        for (int i = 0; i < 4; ++i)
            gll16(Ag + (size_t)(brow + i * 32 + r0) * lda + (k0 + cswz),
                  (char*)As + i * 4096 + w * 1024);
        if constexpr (AEC) {
            // scale current B regs -> LDS, then prefetch next step's regs
            float cf[8] = {cq0.x, cq0.y, cq0.z, cq0.w, cq1.x, cq1.y, cq1.z, cq1.w};
#pragma unroll
            for (int i = 0; i < NWF; ++i) {
                f16x8 ev = bq[i], pv;
#pragma unroll
                for (int j = 0; j < 8; ++j) pv[j] = (f16)((float)ev[j] * cf[j]);
                *(f16x8*)((char*)Bs + i * 4096 + t * 16) = pv;
            }
            if (k0 + 64 < kseg) {
#pragma unroll
                for (int i = 0; i < NWF; ++i)
                    bq[i] = *(const f16x8*)(Bg + (size_t)(bcol + i * 32 + r0) * ldb
                                            + (k0 + 64 + cswz));
                cq0 = *(const float4*)(cb + k0 + 64 + cswz);
                cq1 = *(const float4*)(cb + k0 + 64 + cswz + 4);
            }
        } else {
#pragma unroll
            for (int i = 0; i < NWF; ++i)
                gll16(Bg + (size_t)(bcol + i * 32 + r0) * ldb + (k0 + cswz),
                      (char*)Bs + i * 4096 + w * 1024);
        }
        __syncthreads();

#pragma unroll
        for (int kk = 0; kk < 64; kk += 32) {
            f16x8 aH[4], bH[NWF];
#pragma unroll
            for (int m = 0; m < 4; ++m) {
                int idx = (wr * 64 + m * 16 + lo) * 64 +
                          ((((kk >> 3) + hi) ^ rA7) * 8);
                aH[m] = *(const f16x8*)&As[idx];
            }
#pragma unroll
            for (int n = 0; n < NWF; ++n) {
                int idx = (wc * (BN / 2) + n * 16 + lo) * 64 +
                          ((((kk >> 3) + hi) ^ rA7) * 8);
                bH[n] = *(const f16x8*)&Bs[idx];
            }
#pragma unroll
            for (int m = 0; m < 4; ++m)
#pragma unroll
                for (int n = 0; n < NWF; ++n)
                    acc[m][n] = __builtin_amdgcn_mfma_f32_16x16x32_f16(
                        aH[m], bH[n], acc[m][n], 0, 0, 0);
        }
        __syncthreads();
    }

    if constexpr (OUT == OUT_ESTATS) {
        // ---- phase A: full 128-row block-column max ----
        float mb[NWF];
#pragma unroll
        for (int n = 0; n < NWF; ++n) {
            float ml = acc[0][n][0];
#pragma unroll
            for (int m = 0; m < 4; ++m)
#pragma unroll
                for (int j = 0; j < 4; ++j) ml = fmaxf(ml, acc[m][n][j]);
            ml = fmaxf(ml, __shfl_xor(ml, 16));
            ml = fmaxf(ml, __shfl_xor(ml, 32));
            if (hi == 0) smst[wr * 128 + wc * (BN / 2) + n * 16 + lo] = ml;
        }
        __syncthreads();
#pragma unroll
        for (int n = 0; n < NWF; ++n) {
            int c = wc * (BN / 2) + n * 16 + lo;
            mb[n] = fmaxf(smst[c], smst[128 + c]);
        }
        // ---- phase B: E write (f16) + z partial ----
        float zsum[NWF];
#pragma unroll
        for (int n = 0; n < NWF; ++n) {
            zsum[n] = 0.f;
            int col = bcol + wc * (BN / 2) + n * 16 + lo;
#pragma unroll
            for (int m = 0; m < 4; ++m)
#pragma unroll
                for (int j = 0; j < 4; ++j) {
                    int row = brow + wr * 64 + m * 16 + hi * 4 + j;
                    float e = __expf(acc[m][n][j] - mb[n]);
                    zsum[n] += e;
                    ((f16*)Cp)[(size_t)row * ldc + col] = (f16)e;
                }
        }
        // ---- phase C: z reduce -> mp/zp ----
        __syncthreads();
#pragma unroll
        for (int n = 0; n < NWF; ++n) {
            float zl = zsum[n];
            zl += __shfl_xor(zl, 16);
            zl += __shfl_xor(zl, 32);
            if (hi == 0) smst[256 + wr * 128 + wc * (BN / 2) + n * 16 + lo] = zl;
        }
        __syncthreads();
        if (t < 128) {
            float m0 = smst[t],       m1 = smst[128 + t];
            float z0 = smst[256 + t], z1 = smst[384 + t];
            size_t o = (size_t)(brow >> 7) * 4096 + bcol + t;
            mp[o] = fmaxf(m0, m1);
            zp[o] = z0 + z1;
        }
        return;
    }

    // ---- generic epilogues ----
#pragma unroll
    for (int m = 0; m < 4; ++m) {
#pragma unroll
        for (int n = 0; n < NWF; ++n) {
            if constexpr (OUT == OUT_VT) {
                int row0 = brow + wr * 64 + m * 16 + hi * 4;
                int col  = bcol + wc * (BN / 2) + n * 16 + lo;    // d index
                int bb = row0 >> 12, n0 = row0 & 4095;
                unsigned short u[4];
#pragma unroll
                for (int j = 0; j < 4; ++j) {
                    f16 vb = (f16)acc[m][n][j];
                    u[j] = *(unsigned short*)&vb;
                }
                ushort4 pack = {u[0], u[1], u[2], u[3]};
                *(ushort4*)&((f16*)Cp)[((size_t)(bb * 512 + col) << 12) + n0] = pack;
            } else {
#pragma unroll
                for (int j = 0; j < 4; ++j) {
                    int row = brow + wr * 64 + m * 16 + hi * 4 + j;
                    int col = bcol + wc * (BN / 2) + n * 16 + lo;
                    size_t idx = (size_t)row * ldc + col + zC;
                    float v = acc[m][n][j];
                    if (EPI == EPI_SILU) v = v / (1.f + __expf(-v));
                    if (EPI == EPI_RES)  v += Res[(size_t)row * ldr + col];
                    if (OUT == OUT_F32) ((float*)Cp)[idx] = v;
                    else                ((f16*)Cp)[idx] = (f16)v;
                }
            }
        }
    }
}

// ---- cast x fp32 -> fp16, 8 elems/thread ----
__global__ void cast_x_kernel(const float* __restrict__ x, f16* __restrict__ xf)
{
    size_t i = ((size_t)blockIdx.x * 256 + threadIdx.x) * 8;
    float4 a = *(const float4*)(x + i);
    float4 b = *(const float4*)(x + i + 4);
    f16x8 o;
    o[0] = (f16)a.x; o[1] = (f16)a.y; o[2] = (f16)a.z; o[3] = (f16)a.w;
    o[4] = (f16)b.x; o[5] = (f16)b.y; o[6] = (f16)b.z; o[7] = (f16)b.w;
    *(f16x8*)(xf + i) = o;
}

// ---- transpose + cast all 10 weights to fp16 (z = weight idx) ----
struct WPack { const float* W[10]; f16* H[10]; };

__global__ void transw_all_kernel(WPack p)
{
    const float* W = p.W[blockIdx.z];
    f16* WT = p.H[blockIdx.z];
    __shared__ float tile[32][33];
    int bx = blockIdx.x * 32, by = blockIdx.y * 32;
    int tx = threadIdx.x, ty = threadIdx.y;      // (32, 8)
#pragma unroll
    for (int i = 0; i < 32; i += 8)
        tile[ty + i][tx] = W[(size_t)(by + ty + i) * 512 + bx + tx];
    __syncthreads();
#pragma unroll
    for (int i = 0; i < 32; i += 8)
        WT[(size_t)(bx + ty + i) * 512 + by + tx] = (f16)tile[tx][ty + i];
}

// ---- combine 32 row-block partials -> per-(block,col) PV scale c ----
__global__ void colstats_comb_kernel(const float* __restrict__ mp,
                                     const float* __restrict__ zp,
                                     float* __restrict__ cB)
{
    int col = blockIdx.x * 256 + threadIdx.x;
    float m = -1e30f;
#pragma unroll
    for (int i = 0; i < 32; ++i) m = fmaxf(m, mp[i * 4096 + col]);
    float z = 0.f;
#pragma unroll
    for (int i = 0; i < 32; ++i) z += zp[i * 4096 + col] * __expf(mp[i * 4096 + col] - m);
    float r = 1.f / z;
#pragma unroll
    for (int i = 0; i < 32; ++i)
        cB[i * 4096 + col] = __expf(mp[i * 4096 + col] - m) * r;
}

// ---------------------------------------------------------------------------
extern "C" void kernel_launch(void* const* d_in, const int* in_sizes, int n_in,
                              void* d_out, int out_size, void* d_ws, size_t ws_size,
                              hipStream_t stream)
{
    const int B = 4, N = 4096, D = 512;
    const size_t MALL = (size_t)B * N;          // 16384
    const size_t ND = MALL * D;                 // 8.4M elems
    const size_t NN = (size_t)N * N;            // 16.7M elems
    const size_t WW = (size_t)D * D;            // 262144
    const float* x = (const float*)d_in[0];
    const float* Wf[10];
    for (int i = 0; i < 10; ++i) Wf[i] = (const float*)d_in[1 + i];
    // Wf: 0 qW1, 1 qW2, 2 kW1, 3 kW2, 4 vW1, 5 vW2, 6 aWq, 7 aWk, 8 aWv, 9 Wout

    char* ws = (char*)d_ws;
    size_t off = 0;
    auto carve = [&](size_t bytes) -> char* {
        char* p = ws + off;
        off = (off + bytes + 255) & ~(size_t)255;
        return p;
    };

    // 6 consecutive 32-MiB planes (fp16 halves everything):
    //   A0: xf              -> E[0]
    //   A1: t1v | hv (v)    -> E[1]
    //   A2: t1 (qk, 1024w)  -> E[2]
    //   A3: h  (qk, 1024w)  -> E[3]
    //   F : QK [16384][1024] (Q cols 0-511, K cols 512-1023)
    //   G : VT | O
    // E planes A0..A3 consecutive => uniform stride NN for z-batched PV.
    const size_t PLANE = NN * 2;                 // 33,554,432 B
    f16* A0 = (f16*)carve(PLANE);
    f16* A1 = (f16*)carve(PLANE);
    f16* A2 = (f16*)carve(PLANE);
    f16* A3 = (f16*)carve(PLANE);
    f16* F  = (f16*)carve(PLANE);
    f16* G  = (f16*)carve(PLANE);
    f16* wc1 = (f16*)carve(2 * WW * 2);          // [qW1|kW1]^T
    f16* wc2 = (f16*)carve(2 * WW * 2);          // [qW2|kW2]^T
    f16* wcA = (f16*)carve(2 * WW * 2);          // [aWq|aWk]^T
    f16* wv1 = (f16*)carve(WW * 2);
    f16* wv2 = (f16*)carve(WW * 2);
    f16* wv3 = (f16*)carve(WW * 2);
    f16* wo  = (f16*)carve(WW * 2);
    float* mp = (float*)carve(32 * 4096 * 4);
    float* zp = (float*)carve(32 * 4096 * 4);
    float* cB = (float*)carve((size_t)B * 32 * 4096 * 4);
    // total ~212 MB, well under proven 263 MB.

    f16* xf  = A0;
    f16* t1v = A1;  f16* hv = A1 + ND;
    f16* t1  = A2;                               // [16384][1024]
    f16* h   = A3;                               // [16384][1024]
    f16* QKf = F;
    f16* VT  = G;   f16* O = G + (size_t)B * D * N;
    f16* E_all = A0;                             // planes A0..A3, stride NN
    (void)in_sizes; (void)n_in; (void)out_size; (void)ws_size;

    // ---- input cast + weight transposes ----
    cast_x_kernel<<<dim3((unsigned)(ND / 2048)), 256, 0, stream>>>(x, xf);
    WPack wp;
    wp.W[0] = Wf[0]; wp.H[0] = wc1;       // qW1
    wp.W[1] = Wf[2]; wp.H[1] = wc1 + WW;  // kW1
    wp.W[2] = Wf[1]; wp.H[2] = wc2;       // qW2
    wp.W[3] = Wf[3]; wp.H[3] = wc2 + WW;  // kW2
    wp.W[4] = Wf[6]; wp.H[4] = wcA;       // aWq
    wp.W[5] = Wf[7]; wp.H[5] = wcA + WW;  // aWk
    wp.W[6] = Wf[4]; wp.H[6] = wv1;       // vW1
    wp.W[7] = Wf[5]; wp.H[7] = wv2;       // vW2
    wp.W[8] = Wf[8]; wp.H[8] = wv3;       // aWv
    wp.W[9] = Wf[9]; wp.H[9] = wo;        // Wout
    transw_all_kernel<<<dim3(16, 16, 10), dim3(32, 8), 0, stream>>>(wp);

    // ---- v branch (BN=64; scratch in A1; VT direct) ----
    gemm_f16<64, EPI_SILU, OUT_F16, 0><<<dim3(8, 128), 256, 0, stream>>>(
        xf, wv1, t1v, nullptr, nullptr, nullptr, nullptr,
        512, 512, 512, 512, 512, 0, 0, 0);
    gemm_f16<64, EPI_RES, OUT_F16, 0><<<dim3(8, 128), 256, 0, stream>>>(
        t1v, wv2, hv, x, nullptr, nullptr, nullptr,
        512, 512, 512, 512, 512, 0, 0, 0);
    gemm_f16<64, EPI_NONE, OUT_VT, 0><<<dim3(8, 128), 256, 0, stream>>>(
        hv, wv3, VT, nullptr, nullptr, nullptr, nullptr,
        512, 512, 512, 512, 512, 0, 0, 0);

    // ---- q+k branches: stage1 concat-N, stages 2-3 z=2 ----
    gemm_f16<64, EPI_SILU, OUT_F16, 0><<<dim3(16, 128), 256, 0, stream>>>(
        xf, wc1, t1, nullptr, nullptr, nullptr, nullptr,
        512, 512, 512, 1024, 512, 0, 0, 0);
    gemm_f16<64, EPI_RES, OUT_F16, 0><<<dim3(8, 128, 2), 256, 0, stream>>>(
        t1, wc2, h, x, nullptr, nullptr, nullptr,
        512, 1024, 512, 1024, 512, 512, WW, 512);
    gemm_f16<64, EPI_NONE, OUT_F16, 0><<<dim3(8, 128, 2), 256, 0, stream>>>(
        h, wcA, QKf, nullptr, nullptr, nullptr, nullptr,
        512, 1024, 512, 1024, 512, 512, WW, 512);

    // ---- per batch: QK^T (single fp16 product) -> E + stats; comb -> c ----
    for (int b = 0; b < B; ++b) {
        size_t boff = (size_t)b * N * 1024;
        gemm_f16<128, EPI_NONE, OUT_ESTATS, 0><<<dim3(32, 32), 256, 0, stream>>>(
            QKf + boff, QKf + boff + 512,
            E_all + (size_t)b * NN, nullptr, mp, zp, nullptr,
            512, 1024, 1024, 4096, 4096, 0, 0, 0);
        colstats_comb_kernel<<<16, 256, 0, stream>>>(
            mp, zp, cB + (size_t)b * 32 * 4096);
    }

    // ---- z-batched PV: O[b] = E[b] @ (c[b] * VT[b])^T (B-side AEC) ----
    gemm_f16<64, EPI_NONE, OUT_F16, 1><<<dim3(8, 32, 4), 256, 0, stream>>>(
        E_all, VT, O, nullptr, nullptr, nullptr, cB,
        4096, 4096, 4096, 512, 512,
        NN, (unsigned long long)D * N, (unsigned long long)N * D);

    // ---- final projection: d_out = O @ Wout (f32 out) ----
    gemm_f16<64, EPI_NONE, OUT_F32, 0><<<dim3(8, 128), 256, 0, stream>>>(
        O, wo, d_out, nullptr, nullptr, nullptr, nullptr,
        512, 512, 512, 512, 512, 0, 0, 0);
}

// Round 10
// 377.271 us; speedup vs baseline: 2.0624x; 1.1286x over previous
//
#include <hip/hip_runtime.h>
#include <hip/hip_bf16.h>
#include <stdint.h>
#include <stddef.h>

typedef _Float16 f16;
typedef __attribute__((ext_vector_type(8))) _Float16 f16x8;
typedef __attribute__((ext_vector_type(4))) float f32x4;

#define EPI_NONE 0
#define EPI_SILU 1
#define EPI_RES  2
#define OUT_F16    0
#define OUT_F32    1
#define OUT_VT     3   // write C transposed into VT[b][d][token], token = row
#define OUT_ESTATS 4   // write E=exp(S-m_blk) f16 + per-col block max/sumexp

__device__ __forceinline__ void gll16(const f16* g, char* l) {
    __builtin_amdgcn_global_load_lds(
        (const __attribute__((address_space(1))) void*)g,
        (__attribute__((address_space(3))) void*)l, 16, 0, 0);
}

// ---------------------------------------------------------------------------
// fp16 m97-structure GEMM: C = A @ B^T, f32 accumulate.
// 128xBN tile, BK=64, 4 waves (2x2), mfma_f32_16x16x32_f16.
// LDS XOR-swizzle => 0 bank conflicts (verified r3). XCD-aware bijective
// block swizzle (per-z nwg % 8 == 0; verified r5: ideal FETCH).
// AEC=1 (PV): B-operand scaled on the fly by cScale[z][qblk][k], reg-staged
// with one-step prefetch. OUT_ESTATS (z-batched): E=exp(S-m_blk) f16 write
// + per-(z, row-block, col) max/sumexp partials.
// ---------------------------------------------------------------------------
template<int BN, int EPI, int OUT, int AEC>
__global__ __launch_bounds__(256)
void gemm_f16(const f16* __restrict__ A, const f16* __restrict__ Bm,
              void* __restrict__ Cp, const float* __restrict__ Res,
              float* __restrict__ mp, float* __restrict__ zp,
              const float* __restrict__ cScale,
              int kseg, int lda, int ldb, int ldc, int ldr,
              unsigned long long sA, unsigned long long sB, unsigned long long sC)
{
    constexpr int NWF = BN / 32;

    const f16* Ag = A + (size_t)blockIdx.z * sA;
    const f16* Bg = Bm + (size_t)blockIdx.z * sB;
    const size_t zC = (size_t)blockIdx.z * sC;

    // XCD-aware bijective swizzle on the (x,y) plane (nwg % 8 == 0)
    unsigned nwg = gridDim.x * gridDim.y;
    unsigned lin = blockIdx.y * gridDim.x + blockIdx.x;
    unsigned cpx = nwg >> 3;
    unsigned swz = (lin & 7) * cpx + (lin >> 3);
    unsigned bxs = swz % gridDim.x, bys = swz / gridDim.x;

    const int t    = threadIdx.x;
    const int w    = t >> 6;
    const int lane = t & 63;
    const int wr   = w >> 1, wc = w & 1;
    const int lo   = lane & 15, hi = lane >> 4;
    const int brow = bys * 128;
    const int bcol = bxs * BN;

    __shared__ f16 As[128 * 64];
    __shared__ f16 Bs[BN * 64];
    __shared__ float smst[(OUT == OUT_ESTATS) ? 512 : 4];

    f32x4 acc[4][NWF];
#pragma unroll
    for (int m = 0; m < 4; ++m)
#pragma unroll
        for (int n = 0; n < NWF; ++n)
            acc[m][n] = (f32x4){0.f, 0.f, 0.f, 0.f};

    const int r0 = t >> 3;                             // row in 32-row stripe
    const int cswz = ((t & 7) ^ ((t >> 3) & 7)) * 8;   // inverse-swizzled src
    const int rA7  = lo & 7;                           // read-side row parity

    const float* cb = nullptr;
    f16x8 bq[NWF];
    float4 cq0, cq1;
    if constexpr (AEC) {
        cb = cScale + ((size_t)blockIdx.z * 32 + (brow >> 7)) * 4096;
#pragma unroll
        for (int i = 0; i < NWF; ++i)
            bq[i] = *(const f16x8*)(Bg + (size_t)(bcol + i * 32 + r0) * ldb + cswz);
        cq0 = *(const float4*)(cb + cswz);
        cq1 = *(const float4*)(cb + cswz + 4);
    }

    for (int k0 = 0; k0 < kseg; k0 += 64) {
#pragma unroll
        for (int i = 0; i < 4; ++i)
            gll16(Ag + (size_t)(brow + i * 32 + r0) * lda + (k0 + cswz),
                  (char*)As + i * 4096 + w * 1024);
        if constexpr (AEC) {
            float cf[8] = {cq0.x, cq0.y, cq0.z, cq0.w, cq1.x, cq1.y, cq1.z, cq1.w};
#pragma unroll
            for (int i = 0; i < NWF; ++i) {
                f16x8 ev = bq[i], pv;
#pragma unroll
                for (int j = 0; j < 8; ++j) pv[j] = (f16)((float)ev[j] * cf[j]);
                *(f16x8*)((char*)Bs + i * 4096 + t * 16) = pv;
            }
            if (k0 + 64 < kseg) {
#pragma unroll
                for (int i = 0; i < NWF; ++i)
                    bq[i] = *(const f16x8*)(Bg + (size_t)(bcol + i * 32 + r0) * ldb
                                            + (k0 + 64 + cswz));
                cq0 = *(const float4*)(cb + k0 + 64 + cswz);
                cq1 = *(const float4*)(cb + k0 + 64 + cswz + 4);
            }
        } else {
#pragma unroll
            for (int i = 0; i < NWF; ++i)
                gll16(Bg + (size_t)(bcol + i * 32 + r0) * ldb + (k0 + cswz),
                      (char*)Bs + i * 4096 + w * 1024);
        }
        __syncthreads();

#pragma unroll
        for (int kk = 0; kk < 64; kk += 32) {
            f16x8 aH[4], bH[NWF];
#pragma unroll
            for (int m = 0; m < 4; ++m) {
                int idx = (wr * 64 + m * 16 + lo) * 64 +
                          ((((kk >> 3) + hi) ^ rA7) * 8);
                aH[m] = *(const f16x8*)&As[idx];
            }
#pragma unroll
            for (int n = 0; n < NWF; ++n) {
                int idx = (wc * (BN / 2) + n * 16 + lo) * 64 +
                          ((((kk >> 3) + hi) ^ rA7) * 8);
                bH[n] = *(const f16x8*)&Bs[idx];
            }
#pragma unroll
            for (int m = 0; m < 4; ++m)
#pragma unroll
                for (int n = 0; n < NWF; ++n)
                    acc[m][n] = __builtin_amdgcn_mfma_f32_16x16x32_f16(
                        aH[m], bH[n], acc[m][n], 0, 0, 0);
        }
        __syncthreads();
    }

    if constexpr (OUT == OUT_ESTATS) {
        const size_t zS = (size_t)blockIdx.z * (32 * 4096);
        // ---- phase A: full 128-row block-column max ----
        float mb[NWF];
#pragma unroll
        for (int n = 0; n < NWF; ++n) {
            float ml = acc[0][n][0];
#pragma unroll
            for (int m = 0; m < 4; ++m)
#pragma unroll
                for (int j = 0; j < 4; ++j) ml = fmaxf(ml, acc[m][n][j]);
            ml = fmaxf(ml, __shfl_xor(ml, 16));
            ml = fmaxf(ml, __shfl_xor(ml, 32));
            if (hi == 0) smst[wr * 128 + wc * (BN / 2) + n * 16 + lo] = ml;
        }
        __syncthreads();
#pragma unroll
        for (int n = 0; n < NWF; ++n) {
            int c = wc * (BN / 2) + n * 16 + lo;
            mb[n] = fmaxf(smst[c], smst[128 + c]);
        }
        // ---- phase B: E write (f16) + z partial ----
        float zsum[NWF];
#pragma unroll
        for (int n = 0; n < NWF; ++n) {
            zsum[n] = 0.f;
            int col = bcol + wc * (BN / 2) + n * 16 + lo;
#pragma unroll
            for (int m = 0; m < 4; ++m)
#pragma unroll
                for (int j = 0; j < 4; ++j) {
                    int row = brow + wr * 64 + m * 16 + hi * 4 + j;
                    float e = __expf(acc[m][n][j] - mb[n]);
                    zsum[n] += e;
                    ((f16*)Cp)[(size_t)row * ldc + col + zC] = (f16)e;
                }
        }
        // ---- phase C: z reduce -> mp/zp ----
        __syncthreads();
#pragma unroll
        for (int n = 0; n < NWF; ++n) {
            float zl = zsum[n];
            zl += __shfl_xor(zl, 16);
            zl += __shfl_xor(zl, 32);
            if (hi == 0) smst[256 + wr * 128 + wc * (BN / 2) + n * 16 + lo] = zl;
        }
        __syncthreads();
        if (t < 128) {
            float m0 = smst[t],       m1 = smst[128 + t];
            float z0 = smst[256 + t], z1 = smst[384 + t];
            size_t o = zS + (size_t)(brow >> 7) * 4096 + bcol + t;
            mp[o] = fmaxf(m0, m1);
            zp[o] = z0 + z1;
        }
        return;
    }

    // ---- generic epilogues ----
#pragma unroll
    for (int m = 0; m < 4; ++m) {
#pragma unroll
        for (int n = 0; n < NWF; ++n) {
            if constexpr (OUT == OUT_VT) {
                int row0 = brow + wr * 64 + m * 16 + hi * 4;
                int col  = bcol + wc * (BN / 2) + n * 16 + lo;    // d index
                int bb = row0 >> 12, n0 = row0 & 4095;
                unsigned short u[4];
#pragma unroll
                for (int j = 0; j < 4; ++j) {
                    f16 vb = (f16)acc[m][n][j];
                    u[j] = *(unsigned short*)&vb;
                }
                ushort4 pack = {u[0], u[1], u[2], u[3]};
                *(ushort4*)&((f16*)Cp)[((size_t)(bb * 512 + col) << 12) + n0] = pack;
            } else {
#pragma unroll
                for (int j = 0; j < 4; ++j) {
                    int row = brow + wr * 64 + m * 16 + hi * 4 + j;
                    int col = bcol + wc * (BN / 2) + n * 16 + lo;
                    size_t idx = (size_t)row * ldc + col + zC;
                    float v = acc[m][n][j];
                    if (EPI == EPI_SILU) v = v / (1.f + __expf(-v));
                    if (EPI == EPI_RES)  v += Res[(size_t)row * ldr + col];
                    if (OUT == OUT_F32) ((float*)Cp)[idx] = v;
                    else                ((f16*)Cp)[idx] = (f16)v;
                }
            }
        }
    }
}

// ---- cast x fp32 -> fp16, 8 elems/thread ----
__global__ void cast_x_kernel(const float* __restrict__ x, f16* __restrict__ xf)
{
    size_t i = ((size_t)blockIdx.x * 256 + threadIdx.x) * 8;
    float4 a = *(const float4*)(x + i);
    float4 b = *(const float4*)(x + i + 4);
    f16x8 o;
    o[0] = (f16)a.x; o[1] = (f16)a.y; o[2] = (f16)a.z; o[3] = (f16)a.w;
    o[4] = (f16)b.x; o[5] = (f16)b.y; o[6] = (f16)b.z; o[7] = (f16)b.w;
    *(f16x8*)(xf + i) = o;
}

// ---- transpose + cast all 10 weights to fp16 (z = weight idx) ----
struct WPack { const float* W[10]; f16* H[10]; };

__global__ void transw_all_kernel(WPack p)
{
    const float* W = p.W[blockIdx.z];
    f16* WT = p.H[blockIdx.z];
    __shared__ float tile[32][33];
    int bx = blockIdx.x * 32, by = blockIdx.y * 32;
    int tx = threadIdx.x, ty = threadIdx.y;      // (32, 8)
#pragma unroll
    for (int i = 0; i < 32; i += 8)
        tile[ty + i][tx] = W[(size_t)(by + ty + i) * 512 + bx + tx];
    __syncthreads();
#pragma unroll
    for (int i = 0; i < 32; i += 8)
        WT[(size_t)(bx + ty + i) * 512 + by + tx] = (f16)tile[tx][ty + i];
}

// ---- combine 32 row-block partials -> per-(z, block, col) PV scale c ----
__global__ void colstats_comb_kernel(const float* __restrict__ mp,
                                     const float* __restrict__ zp,
                                     float* __restrict__ cB)
{
    size_t base = (size_t)blockIdx.y * (32 * 4096);
    int col = blockIdx.x * 256 + threadIdx.x;
    float m = -1e30f;
#pragma unroll
    for (int i = 0; i < 32; ++i) m = fmaxf(m, mp[base + i * 4096 + col]);
    float z = 0.f;
#pragma unroll
    for (int i = 0; i < 32; ++i)
        z += zp[base + i * 4096 + col] * __expf(mp[base + i * 4096 + col] - m);
    float r = 1.f / z;
#pragma unroll
    for (int i = 0; i < 32; ++i)
        cB[base + i * 4096 + col] = __expf(mp[base + i * 4096 + col] - m) * r;
}

// ---------------------------------------------------------------------------
extern "C" void kernel_launch(void* const* d_in, const int* in_sizes, int n_in,
                              void* d_out, int out_size, void* d_ws, size_t ws_size,
                              hipStream_t stream)
{
    const int B = 4, N = 4096, D = 512;
    const size_t MALL = (size_t)B * N;          // 16384
    const size_t ND = MALL * D;                 // 8,388,608 elems (16 MiB f16)
    const size_t NN = (size_t)N * N;            // 16,777,216 elems (32 MiB f16)
    const size_t WW = (size_t)D * D;            // 262144
    const float* x = (const float*)d_in[0];
    const float* Wf[10];
    for (int i = 0; i < 10; ++i) Wf[i] = (const float*)d_in[1 + i];
    // Wf: 0 qW1, 1 qW2, 2 kW1, 3 kW2, 4 vW1, 5 vW2, 6 aWq, 7 aWk, 8 aWv, 9 Wout

    char* ws = (char*)d_ws;
    size_t off = 0;
    auto carve = [&](size_t bytes) -> char* {
        char* p = ws + off;
        off = (off + bytes + 255) & ~(size_t)255;
        return p;
    };

    // E region: 128 MiB (4 planes, stride NN). Before QK^T it hosts
    //   xf [0,16M) | t1 [16M,64M) | h [64M,112M)   (all dead at E-write time)
    const size_t PLANE = NN * 2;                 // 33,554,432 B
    f16* E_all = (f16*)carve(4 * PLANE);
    f16* QKf   = (f16*)carve(PLANE);             // [16384][1024] Q|K
    f16* VT    = (f16*)carve((size_t)B * D * N * 2);   // 16 MiB
    f16* O     = (f16*)carve(ND * 2);                  // 16 MiB
    f16* wc1   = (f16*)carve(3 * WW * 2);        // [qW1|kW1|vW1]^T
    f16* wc2   = (f16*)carve(3 * WW * 2);        // [qW2|kW2|vW2]^T
    f16* wcA   = (f16*)carve(2 * WW * 2);        // [aWq|aWk]^T
    f16* wv3   = (f16*)carve(WW * 2);            // aWv^T
    f16* wo    = (f16*)carve(WW * 2);            // Wout^T
    float* mp  = (float*)carve((size_t)B * 32 * 4096 * 4);
    float* zp  = (float*)carve((size_t)B * 32 * 4096 * 4);
    float* cB  = (float*)carve((size_t)B * 32 * 4096 * 4);
    // total ~203 MB, under proven 263 MB.

    f16* xf = E_all;                             // 16 MiB
    f16* t1 = E_all + ND;                        // [16384][1536], 48 MiB
    f16* h  = t1 + MALL * 1536;                  // [16384][1536], 48 MiB
    (void)in_sizes; (void)n_in; (void)out_size; (void)ws_size;

    // ---- input cast + weight transposes ----
    cast_x_kernel<<<dim3((unsigned)(ND / 2048)), 256, 0, stream>>>(x, xf);
    WPack wp;
    wp.W[0] = Wf[0]; wp.H[0] = wc1;            // qW1
    wp.W[1] = Wf[2]; wp.H[1] = wc1 + WW;       // kW1
    wp.W[2] = Wf[4]; wp.H[2] = wc1 + 2 * WW;   // vW1
    wp.W[3] = Wf[1]; wp.H[3] = wc2;            // qW2
    wp.W[4] = Wf[3]; wp.H[4] = wc2 + WW;       // kW2
    wp.W[5] = Wf[5]; wp.H[5] = wc2 + 2 * WW;   // vW2
    wp.W[6] = Wf[6]; wp.H[6] = wcA;            // aWq
    wp.W[7] = Wf[7]; wp.H[7] = wcA + WW;       // aWk
    wp.W[8] = Wf[8]; wp.H[8] = wv3;            // aWv
    wp.W[9] = Wf[9]; wp.H[9] = wo;             // Wout
    transw_all_kernel<<<dim3(16, 16, 10), dim3(32, 8), 0, stream>>>(wp);

    // ---- fused ResiMLP stage 1: t1 = silu(x @ [qW1|kW1|vW1]) ----
    gemm_f16<128, EPI_SILU, OUT_F16, 0><<<dim3(12, 128), 256, 0, stream>>>(
        xf, wc1, t1, nullptr, nullptr, nullptr, nullptr,
        512, 512, 512, 1536, 512, 0, 0, 0);
    // ---- stage 2 (z=3): h_z = t1_z @ W2_z + x ----
    gemm_f16<128, EPI_RES, OUT_F16, 0><<<dim3(4, 128, 3), 256, 0, stream>>>(
        t1, wc2, h, x, nullptr, nullptr, nullptr,
        512, 1536, 512, 1536, 512, 512, WW, 512);
    // ---- stage 3 q,k (z=2): QKf_z = h_z @ aW_z ----
    gemm_f16<128, EPI_NONE, OUT_F16, 0><<<dim3(4, 128, 2), 256, 0, stream>>>(
        h, wcA, QKf, nullptr, nullptr, nullptr, nullptr,
        512, 1536, 512, 1024, 512, 512, WW, 512);
    // ---- stage 3 v: VT = (h_v @ aWv)^T ----
    gemm_f16<128, EPI_NONE, OUT_VT, 0><<<dim3(4, 128), 256, 0, stream>>>(
        h + 1024, wv3, VT, nullptr, nullptr, nullptr, nullptr,
        512, 1536, 512, 512, 512, 0, 0, 0);

    // ---- QK^T z=4: E[b] = exp(Q_b K_b^T - m_blk) + per-block stats ----
    gemm_f16<128, EPI_NONE, OUT_ESTATS, 0><<<dim3(32, 32, 4), 256, 0, stream>>>(
        QKf, QKf + 512, E_all, nullptr, mp, zp, nullptr,
        512, 1024, 1024, 4096, 4096,
        (unsigned long long)N * 1024, (unsigned long long)N * 1024, NN);
    // ---- combine partials -> cB[b][blk][col] ----
    colstats_comb_kernel<<<dim3(16, 4), 256, 0, stream>>>(mp, zp, cB);

    // ---- z-batched PV: O[b] = E[b] @ (c[b] * VT[b])^T (B-side AEC) ----
    gemm_f16<64, EPI_NONE, OUT_F16, 1><<<dim3(8, 32, 4), 256, 0, stream>>>(
        E_all, VT, O, nullptr, nullptr, nullptr, cB,
        4096, 4096, 4096, 512, 512,
        NN, (unsigned long long)D * N, (unsigned long long)N * D);

    // ---- final projection: d_out = O @ Wout (f32 out) ----
    gemm_f16<128, EPI_NONE, OUT_F32, 0><<<dim3(4, 128), 256, 0, stream>>>(
        O, wo, d_out, nullptr, nullptr, nullptr, nullptr,
        512, 512, 512, 512, 512, 0, 0, 0);
}